// Round 6
// baseline (40.536 us; speedup 1.0000x reference)
//
#include <hip/hip_runtime.h>

#define NDENSE 13
#define NSPARSE 26
#define ROW_F4 156   // 39*16/4 float4 per v row
#define BATCH 4096

// Work decomposition for phase 1:
//   19 "full" slices: W=8 float4 (128 B granule), RPB=32 rows, 128 chunks -> ids 0..2431
//    1 "narrow" slice: W=4 (64 B), RPB=64 rows, 64 chunks
// XCD x (= blockIdx%8, HW round-robin): x<7 -> full ids [308x, 308x+308)
//   x=7 -> full ids [2156, 2432) + the 64 narrow chunks. Equal work units/XCD.
// Per-XCD temporal order is chunk-major within slice -> L2 working set at any
// instant = one slice (3.33 MB / 1.66 MB) -> L2-resident.

__global__ __launch_bounds__(256) void ffm_slice4(
    const float*  __restrict__ dense,    // [B,13]
    const int*    __restrict__ sparse,   // [B,26]
    const float4* __restrict__ v4,       // [26013*156]
    float4*       __restrict__ ff)       // [B*156] field_f output
{
    const int x = blockIdx.x & 7;
    const int i = blockIdx.x >> 3;

    bool narrow = false;
    int fid = 0, chunk, W, sb, rpb;
    if (x < 7) {
        if (i >= 308) return;
        fid = 308 * x + i;
    } else {
        if (i >= 340) return;
        if (i < 276) fid = 2156 + i;
        else { narrow = true; chunk = i - 276; }
    }
    if (!narrow) {
        const int slice = fid >> 7;          // 0..18
        chunk = fid & 127;
        W = 8; sb = slice * 8; rpb = 32;
    } else {
        W = 4; sb = 152; rpb = 64;
    }
    const int row0 = chunk * rpb;

    __shared__ int    vrow_s[64 * NSPARSE];  // 6656 B (max rpb=64)
    __shared__ float  dsh   [64 * NDENSE];   // 3328 B
    __shared__ float4 vsh   [NDENSE * 8];    // 1664 B: v[:13] slice columns

    const int t = threadIdx.x;
    for (int q = t; q < rpb * NSPARSE; q += 256) {
        const int r = q / NSPARSE, j = q % NSPARSE;
        vrow_s[q] = sparse[(row0 + r) * NSPARSE + j] + NDENSE + 1000 * j;
    }
    for (int q = t; q < rpb * NDENSE; q += 256)
        dsh[q] = dense[row0 * NDENSE + q];
    for (int q = t; q < NDENSE * W; q += 256)
        vsh[q] = v4[(q / W) * ROW_F4 + sb + (q % W)];
    __syncthreads();

    const int lane = t & 63;
    const int wv   = t >> 6;
    int group, c;
    if (!narrow) { group = lane >> 3; c = lane & 7; }
    else         { group = lane >> 2; c = lane & 3; }
    const int rl = wv * (rpb >> 2) + group;   // local row, 0..rpb-1
    const int fb = sb + c;                    // f4 column in v row

    // Dense part from LDS (no global traffic)
    float4 acc = make_float4(0.f, 0.f, 0.f, 0.f);
#pragma unroll
    for (int d = 0; d < NDENSE; ++d) {
        const float  wg = dsh[rl * NDENSE + d];
        const float4 vv = vsh[d * W + c];
        acc.x += wg * vv.x; acc.y += wg * vv.y;
        acc.z += wg * vv.z; acc.w += wg * vv.w;
    }

    // Indices to registers, then 26 independent gathers. sched_barrier(0)
    // forbids the compiler from sinking loads into the add loop -> all 26
    // in flight (max MLP).
    int vrr[NSPARSE];
#pragma unroll
    for (int j = 0; j < NSPARSE; ++j) vrr[j] = vrow_s[rl * NSPARSE + j];

    float4 g[NSPARSE];
#pragma unroll
    for (int j = 0; j < NSPARSE; ++j)
        g[j] = v4[(unsigned)vrr[j] * ROW_F4 + fb];

    __builtin_amdgcn_sched_barrier(0);

#pragma unroll
    for (int j = 0; j < NSPARSE; ++j) {
        acc.x += g[j].x; acc.y += g[j].y; acc.z += g[j].z; acc.w += g[j].w;
    }

    ff[(unsigned)(row0 + rl) * ROW_F4 + fb] = acc;
}

// ---------------------------------------------------------------------------
// Phase 2: FM reduction over materialized field_f + first order. (R3-proven)
__global__ __launch_bounds__(256) void ffm_final(
    const float*  __restrict__ dense,
    const int*    __restrict__ sparse,
    const float*  __restrict__ w0,
    const float*  __restrict__ w,
    const float4* __restrict__ ff,
    float*        __restrict__ out)
{
    const int wave = threadIdx.x >> 6;
    const int lane = threadIdx.x & 63;
    const int b = blockIdx.x * 4 + wave;

    float4 s = make_float4(0.f, 0.f, 0.f, 0.f);
    float  sq = 0.f;
#pragma unroll
    for (int p = 0; p < 3; ++p) {
        const int e4 = lane + 64 * p;
        if (e4 < ROW_F4) {
            const float4 acc = ff[(unsigned)b * ROW_F4 + e4];
            s.x += acc.x; s.y += acc.y; s.z += acc.z; s.w += acc.w;
            sq  += acc.x*acc.x + acc.y*acc.y + acc.z*acc.z + acc.w*acc.w;
        }
    }
#pragma unroll
    for (int m = 4; m <= 32; m <<= 1) {
        s.x += __shfl_xor(s.x, m); s.y += __shfl_xor(s.y, m);
        s.z += __shfl_xor(s.z, m); s.w += __shfl_xor(s.w, m);
    }
    float s2 = s.x*s.x + s.y*s.y + s.z*s.z + s.w*s.w;
    s2 += __shfl_xor(s2, 1);
    s2 += __shfl_xor(s2, 2);
#pragma unroll
    for (int m = 1; m <= 32; m <<= 1) sq += __shfl_xor(sq, m);

    float fo = 0.f;
    if (lane < NSPARSE) fo = w[sparse[b * NSPARSE + lane] + NDENSE + 1000 * lane];
    if (lane < NDENSE)  fo += dense[b * NDENSE + lane] * w[lane];
#pragma unroll
    for (int m = 1; m <= 32; m <<= 1) fo += __shfl_xor(fo, m);

    if (lane == 0) out[b] = w0[0] + fo + 0.5f * (s2 - sq);
}

// ---------------------------------------------------------------------------
// Fallback: R1 fused kernel (only if ws too small for field_f buffer).
__global__ __launch_bounds__(256) void ffm_fused(
    const float* __restrict__ dense, const int* __restrict__ sparse,
    const float* __restrict__ w0, const float* __restrict__ w,
    const float4* __restrict__ v4, float* __restrict__ out)
{
    const int wave = threadIdx.x >> 6;
    const int lane = threadIdx.x & 63;
    const int b = blockIdx.x * 4 + wave;

    float dv[NDENSE];
#pragma unroll
    for (int d = 0; d < NDENSE; ++d) dv[d] = dense[b * NDENSE + d];
    int myidx = 0;
    if (lane < NSPARSE) myidx = sparse[b * NSPARSE + lane] + NDENSE + 1000 * lane;

    float4 s = make_float4(0.f, 0.f, 0.f, 0.f);
    float  sq = 0.f;
#pragma unroll
    for (int p = 0; p < 3; ++p) {
        const int e4 = lane + 64 * p;
        if (e4 < ROW_F4) {
            float4 acc = make_float4(0.f, 0.f, 0.f, 0.f);
#pragma unroll
            for (int d = 0; d < NDENSE; ++d) {
                const float4 vv = v4[d * ROW_F4 + e4];
                acc.x += dv[d]*vv.x; acc.y += dv[d]*vv.y;
                acc.z += dv[d]*vv.z; acc.w += dv[d]*vv.w;
            }
#pragma unroll
            for (int j = 0; j < NSPARSE; ++j) {
                const int ij = __shfl(myidx, j);
                const float4 vv = v4[(size_t)ij * ROW_F4 + e4];
                acc.x += vv.x; acc.y += vv.y; acc.z += vv.z; acc.w += vv.w;
            }
            s.x += acc.x; s.y += acc.y; s.z += acc.z; s.w += acc.w;
            sq  += acc.x*acc.x + acc.y*acc.y + acc.z*acc.z + acc.w*acc.w;
        }
    }
#pragma unroll
    for (int m = 4; m <= 32; m <<= 1) {
        s.x += __shfl_xor(s.x, m); s.y += __shfl_xor(s.y, m);
        s.z += __shfl_xor(s.z, m); s.w += __shfl_xor(s.w, m);
    }
    float s2 = s.x*s.x + s.y*s.y + s.z*s.z + s.w*s.w;
    s2 += __shfl_xor(s2, 1);
    s2 += __shfl_xor(s2, 2);
#pragma unroll
    for (int m = 1; m <= 32; m <<= 1) sq += __shfl_xor(sq, m);
    float fo = 0.f;
    if (lane < NSPARSE) fo = w[myidx];
    if (lane < NDENSE)  fo += dense[b * NDENSE + lane] * w[lane];
#pragma unroll
    for (int m = 1; m <= 32; m <<= 1) fo += __shfl_xor(fo, m);
    if (lane == 0) out[b] = w0[0] + fo + 0.5f * (s2 - sq);
}

extern "C" void kernel_launch(void* const* d_in, const int* in_sizes, int n_in,
                              void* d_out, int out_size, void* d_ws, size_t ws_size,
                              hipStream_t stream) {
    const float*  dense  = (const float*)d_in[0];
    const int*    sparse = (const int*)d_in[1];
    const float*  w0     = (const float*)d_in[2];
    const float*  w      = (const float*)d_in[3];
    const float4* v4     = (const float4*)d_in[4];
    float* out = (float*)d_out;

    const size_t ff_bytes = (size_t)BATCH * ROW_F4 * sizeof(float4); // 10.2 MB

    if (ws_size >= ff_bytes) {
        float4* ffp = (float4*)d_ws;
        // 8 XCD lanes x 340 slots (some idle) = 2720 blocks
        hipLaunchKernelGGL(ffm_slice4, dim3(8 * 340), dim3(256), 0, stream,
                           dense, sparse, v4, ffp);
        hipLaunchKernelGGL(ffm_final, dim3(BATCH / 4), dim3(256), 0, stream,
                           dense, sparse, w0, w, ffp, out);
    } else {
        hipLaunchKernelGGL(ffm_fused, dim3(BATCH / 4), dim3(256), 0, stream,
                           dense, sparse, w0, w, v4, out);
    }
}

// Round 7
// 40.193 us; speedup vs baseline: 1.0085x; 1.0085x over previous
//
#include <hip/hip_runtime.h>
#include <hip/hip_fp16.h>

#define NDENSE 13
#define NSPARSE 26
#define ROW_F4 156     // 39*16/4 float4 per fp32 v row
#define BATCH 4096
#define VROWS 26013
#define ROW_U4H 80     // padded f16 row = 80 uint4 = 1280 B (640 halves, 624 used)
#define NSLICE 10      // 10 slices x 64 halves (4 fields) per v row
#define RPB 32         // rows per block in gather
#define PCHUNK 128     // chunks = 4096/32
#define PSTRIDE 20     // floats per (slice,row) partial record: s[16], sq, pad

// ---------------------------------------------------------------------------
// Kernel 0: convert v fp32 -> f16, rows padded 624 -> 640 halves (zeros).
__global__ __launch_bounds__(256) void conv_f16(
    const float* __restrict__ v, uint4* __restrict__ vh)
{
    const unsigned t = blockIdx.x * 256 + threadIdx.x;
    if (t >= (unsigned)VROWS * ROW_U4H) return;
    const unsigned row = t / ROW_U4H, seg = t % ROW_U4H;
    union { __half2 h2[4]; uint4 u; } o;
    if (seg < 78) {
        const float4* src = (const float4*)(v + (size_t)row * 624 + seg * 8);
        const float4 a = src[0], b = src[1];
        o.h2[0] = __floats2half2_rn(a.x, a.y);
        o.h2[1] = __floats2half2_rn(a.z, a.w);
        o.h2[2] = __floats2half2_rn(b.x, b.y);
        o.h2[3] = __floats2half2_rn(b.z, b.w);
    } else {
        o.u = make_uint4(0u, 0u, 0u, 0u);   // pad field 39 = zeros
    }
    vh[t] = o.u;
}

// ---------------------------------------------------------------------------
// Kernel 1: XCD-pinned f16 sliced gather + fused per-slice FM partials.
// Slice = 4 fields = 128 B of an f16 row; WS = 26013*128B = 3.3MB -> L2/XCD.
// Per row: acc (8 f32) = dense part (LDS, fp32) + sum of 26 f16 gathers.
// Fused reduction -> s_part[16], sq_part written to PART[slice][b][20].
__global__ __launch_bounds__(256) void ffm_slice5(
    const float* __restrict__ dense,     // [B,13]
    const int*   __restrict__ sparse,    // [B,26]
    const float* __restrict__ v,         // fp32 v for the dense slice staging
    const uint4* __restrict__ vh,        // [26013*80] f16 rows
    float*       __restrict__ part)      // [10][4096][20]
{
    const int x = blockIdx.x & 7;
    const int i = blockIdx.x >> 3;              // 0..159 per XCD
    const int fid = x * 160 + i;                // 0..1279
    const int s0 = fid >> 7;                    // slice 0..9
    const int chunk = fid & (PCHUNK - 1);
    const int row0 = chunk * RPB;

    __shared__ int   vrow_s[RPB * NSPARSE];     // 3328 B
    __shared__ float dsh   [RPB * NDENSE];      // 1664 B
    __shared__ float vsh   [NDENSE * 64];       // 3328 B: fp32 dense v-slice

    const int t = threadIdx.x;
    for (int q = t; q < RPB * NSPARSE; q += 256) {
        const int r = q / NSPARSE, j = q % NSPARSE;
        vrow_s[q] = sparse[(row0 + r) * NSPARSE + j] + NDENSE + 1000 * j;
    }
    for (int q = t; q < RPB * NDENSE; q += 256)
        dsh[q] = dense[row0 * NDENSE + q];
    for (int q = t; q < NDENSE * 64; q += 256) {
        const int d = q >> 6, h = q & 63, col = s0 * 64 + h;
        vsh[q] = (col < 624) ? v[(size_t)d * 624 + col] : 0.f;
    }
    __syncthreads();

    const int lane = t & 63;
    const int wv   = t >> 6;
    const int rl   = wv * 8 + (lane >> 3);      // local row 0..31
    const int c    = lane & 7;                  // 16B segment within slice
    const int rg   = row0 + rl;

    float acc[8];
#pragma unroll
    for (int q = 0; q < 8; ++q) acc[q] = 0.f;

    // Dense part from LDS (fp32, exact)
#pragma unroll
    for (int d = 0; d < NDENSE; ++d) {
        const float wg = dsh[rl * NDENSE + d];
#pragma unroll
        for (int q = 0; q < 8; ++q)
            acc[q] += wg * vsh[d * 64 + c * 8 + q];
    }

    // 26 f16 gathers (16 B each), decode and accumulate
#pragma unroll
    for (int j = 0; j < NSPARSE; ++j) {
        const unsigned vr = (unsigned)vrow_s[rl * NSPARSE + j];
        union { uint4 u; __half2 h2[4]; } g;
        g.u = vh[(size_t)vr * ROW_U4H + s0 * 8 + c];
#pragma unroll
        for (int q = 0; q < 4; ++q) {
            const float2 f = __half22float2(g.h2[q]);
            acc[2 * q]     += f.x;
            acc[2 * q + 1] += f.y;
        }
    }

    // sq from original per-field acc, reduced over the row's 8 lanes
    float sq = 0.f;
#pragma unroll
    for (int q = 0; q < 8; ++q) sq += acc[q] * acc[q];
    sq += __shfl_xor(sq, 1);
    sq += __shfl_xor(sq, 2);
    sq += __shfl_xor(sq, 4);

    // s: sum the 4 fields sharing this k-half (lanes with same c&1)
#pragma unroll
    for (int q = 0; q < 8; ++q) acc[q] += __shfl_xor(acc[q], 2);
#pragma unroll
    for (int q = 0; q < 8; ++q) acc[q] += __shfl_xor(acc[q], 4);

    float* rec = part + ((size_t)s0 * BATCH + rg) * PSTRIDE;
    if (c < 2) {   // c=0: s[0..7], c=1: s[8..15]
        float4* p = (float4*)(rec + c * 8);
        p[0] = make_float4(acc[0], acc[1], acc[2], acc[3]);
        p[1] = make_float4(acc[4], acc[5], acc[6], acc[7]);
    }
    if (c == 2) rec[16] = sq;
}

// ---------------------------------------------------------------------------
// Kernel 2: combine 10 slice-partials + first order.
__global__ __launch_bounds__(256) void ffm_final5(
    const float* __restrict__ dense,
    const int*   __restrict__ sparse,
    const float* __restrict__ w0,
    const float* __restrict__ w,
    const float* __restrict__ part,
    float*       __restrict__ out)
{
    const int wave = threadIdx.x >> 6;
    const int lane = threadIdx.x & 63;
    const int b = blockIdx.x * 4 + wave;

    float sk = 0.f, sqs = 0.f;
#pragma unroll
    for (int s = 0; s < NSLICE; ++s) {
        const float* rec = part + ((size_t)s * BATCH + b) * PSTRIDE;
        if (lane < 16) sk  += rec[lane];
        if (lane == 0) sqs += rec[16];
    }
    float s2 = sk * sk;    // lanes >=16 hold 0
#pragma unroll
    for (int m = 1; m <= 32; m <<= 1) s2 += __shfl_xor(s2, m);

    float fo = 0.f;
    if (lane < NSPARSE) fo = w[sparse[b * NSPARSE + lane] + NDENSE + 1000 * lane];
    if (lane < NDENSE)  fo += dense[b * NDENSE + lane] * w[lane];
#pragma unroll
    for (int m = 1; m <= 32; m <<= 1) fo += __shfl_xor(fo, m);

    if (lane == 0) out[b] = w0[0] + fo + 0.5f * (s2 - sqs);
}

// ---------------------------------------------------------------------------
// Fallback A (ws >= 10.2MB): R5-proven fp32 slice + final pair.
__global__ __launch_bounds__(256) void ffm_slice3(
    const float* __restrict__ dense, const int* __restrict__ sparse,
    const float4* __restrict__ v4, float4* __restrict__ ff)
{
    const int xcd = blockIdx.x & 7;
    const int rest = blockIdx.x >> 3;
    const int slice = xcd * 5 + (rest >> 6);
    const int chunk = rest & 63;

    __shared__ int    vrow_s[64 * NSPARSE];
    __shared__ float  dshf  [64 * NDENSE];
    __shared__ float4 vshf  [NDENSE * 4];

    if (slice >= 39) return;
    const int t = threadIdx.x;
    const int row0 = chunk * 64;
    for (int q = t; q < 64 * NSPARSE; q += 256) {
        const int r = q / NSPARSE, j = q % NSPARSE;
        vrow_s[q] = sparse[(row0 + r) * NSPARSE + j] + NDENSE + 1000 * j;
    }
    for (int q = t; q < 64 * NDENSE; q += 256)
        dshf[q] = dense[row0 * NDENSE + q];
    if (t < NDENSE * 4)
        vshf[t] = v4[(t >> 2) * ROW_F4 + slice * 4 + (t & 3)];
    __syncthreads();

    const int lane = t & 63;
    const int wv = t >> 6;
    const int rl = (wv << 4) + (lane >> 2);
    const int c = lane & 3;
    const int fb = slice * 4 + c;

    float4 acc = make_float4(0.f, 0.f, 0.f, 0.f);
#pragma unroll
    for (int d = 0; d < NDENSE; ++d) {
        const float wg = dshf[rl * NDENSE + d];
        const float4 vv = vshf[d * 4 + c];
        acc.x += wg * vv.x; acc.y += wg * vv.y;
        acc.z += wg * vv.z; acc.w += wg * vv.w;
    }
#pragma unroll
    for (int j = 0; j < NSPARSE; ++j) {
        const float4 g = v4[(unsigned)vrow_s[rl * NSPARSE + j] * ROW_F4 + fb];
        acc.x += g.x; acc.y += g.y; acc.z += g.z; acc.w += g.w;
    }
    ff[(unsigned)(row0 + rl) * ROW_F4 + fb] = acc;
}

__global__ __launch_bounds__(256) void ffm_final(
    const float* __restrict__ dense, const int* __restrict__ sparse,
    const float* __restrict__ w0, const float* __restrict__ w,
    const float4* __restrict__ ff, float* __restrict__ out)
{
    const int wave = threadIdx.x >> 6;
    const int lane = threadIdx.x & 63;
    const int b = blockIdx.x * 4 + wave;

    float4 s = make_float4(0.f, 0.f, 0.f, 0.f);
    float sq = 0.f;
#pragma unroll
    for (int p = 0; p < 3; ++p) {
        const int e4 = lane + 64 * p;
        if (e4 < ROW_F4) {
            const float4 a = ff[(unsigned)b * ROW_F4 + e4];
            s.x += a.x; s.y += a.y; s.z += a.z; s.w += a.w;
            sq += a.x*a.x + a.y*a.y + a.z*a.z + a.w*a.w;
        }
    }
#pragma unroll
    for (int m = 4; m <= 32; m <<= 1) {
        s.x += __shfl_xor(s.x, m); s.y += __shfl_xor(s.y, m);
        s.z += __shfl_xor(s.z, m); s.w += __shfl_xor(s.w, m);
    }
    float s2 = s.x*s.x + s.y*s.y + s.z*s.z + s.w*s.w;
    s2 += __shfl_xor(s2, 1);
    s2 += __shfl_xor(s2, 2);
#pragma unroll
    for (int m = 1; m <= 32; m <<= 1) sq += __shfl_xor(sq, m);
    float fo = 0.f;
    if (lane < NSPARSE) fo = w[sparse[b * NSPARSE + lane] + NDENSE + 1000 * lane];
    if (lane < NDENSE)  fo += dense[b * NDENSE + lane] * w[lane];
#pragma unroll
    for (int m = 1; m <= 32; m <<= 1) fo += __shfl_xor(fo, m);
    if (lane == 0) out[b] = w0[0] + fo + 0.5f * (s2 - sq);
}

extern "C" void kernel_launch(void* const* d_in, const int* in_sizes, int n_in,
                              void* d_out, int out_size, void* d_ws, size_t ws_size,
                              hipStream_t stream) {
    const float*  dense  = (const float*)d_in[0];
    const int*    sparse = (const int*)d_in[1];
    const float*  w0     = (const float*)d_in[2];
    const float*  w      = (const float*)d_in[3];
    const float*  v      = (const float*)d_in[4];
    const float4* v4     = (const float4*)d_in[4];
    float* out = (float*)d_out;

    const size_t vh_bytes   = (size_t)VROWS * ROW_U4H * 16;            // 33.3 MB
    const size_t part_bytes = (size_t)NSLICE * BATCH * PSTRIDE * 4;    // 3.3 MB
    const size_t ff_bytes   = (size_t)BATCH * ROW_F4 * sizeof(float4); // 10.2 MB

    if (ws_size >= vh_bytes + part_bytes) {
        uint4* vh   = (uint4*)d_ws;
        float* prt  = (float*)((char*)d_ws + vh_bytes);
        const unsigned convN = (unsigned)VROWS * ROW_U4H;
        hipLaunchKernelGGL(conv_f16, dim3((convN + 255) / 256), dim3(256), 0, stream,
                           v, vh);
        hipLaunchKernelGGL(ffm_slice5, dim3(8 * 160), dim3(256), 0, stream,
                           dense, sparse, v, vh, prt);
        hipLaunchKernelGGL(ffm_final5, dim3(BATCH / 4), dim3(256), 0, stream,
                           dense, sparse, w0, w, prt, out);
    } else if (ws_size >= ff_bytes) {
        float4* ffp = (float4*)d_ws;
        hipLaunchKernelGGL(ffm_slice3, dim3(8 * 5 * 64), dim3(256), 0, stream,
                           dense, sparse, v4, ffp);
        hipLaunchKernelGGL(ffm_final, dim3(BATCH / 4), dim3(256), 0, stream,
                           dense, sparse, w0, w, ffp, out);
    }
}